// Round 1
// baseline (75.901 us; speedup 1.0000x reference)
//
#include <hip/hip_runtime.h>
#include <stdint.h>
#include <stddef.h>

// Actor_DeepSet: rows = 131072 (= 16384 batches x 8 agents), OBS=64, HIDDEN=128, OUT=16.
// Fully fused bf16-MFMA kernel: 64 rows (8 batches) per 256-thread block.
// Feature-roll trick: h1_other(agent i) = sum_{j=1..7} relu( roll_{i+1}(x_j) . w1o^T + b1o )
// -> per wave: 8 k-major passes with compile-time roll, A-frags built from aligned
//    ds_read_b128 windows + constant 16-bit funnel shifts.

typedef __attribute__((ext_vector_type(8))) short short8;       // 8 x bf16 (4 VGPR)
typedef __attribute__((ext_vector_type(4))) float floatx4;      // MFMA C/D
typedef __attribute__((ext_vector_type(4))) unsigned int uintx4;
typedef __attribute__((ext_vector_type(4))) float float4v;

static __device__ __forceinline__ unsigned short f2bf(float f) {
    unsigned int x = __float_as_uint(f);
    x += 0x7fffu + ((x >> 16) & 1u);          // round-to-nearest-even
    return (unsigned short)(x >> 16);
}

static __device__ __forceinline__ floatx4 mfma16(short8 a, short8 b, floatx4 c) {
    return __builtin_amdgcn_mfma_f32_16x16x32_bf16(a, b, c, 0, 0, 0);
}

// ---- prologue: convert all weights to bf16 into d_ws ----
// ws layout (ushort elems): w1[8192] | w1o[8192] | w2[32768] | wv[2048]  (total 51200)
__global__ void cvt_weights(const float* __restrict__ w1, const float* __restrict__ w1o,
                            const float* __restrict__ w2, const float* __restrict__ wv,
                            unsigned short* __restrict__ ws) {
    int i = blockIdx.x * 256 + threadIdx.x;   // grid sized exactly 51200/256 = 200 blocks
    float v;
    if (i < 8192)       v = w1[i];
    else if (i < 16384) v = w1o[i - 8192];
    else if (i < 49152) v = w2[i - 16384];
    else                v = wv[i - 49152];
    ws[i] = f2bf(v);
}

__launch_bounds__(256, 2)
__global__ void actor_fused(const float* __restrict__ X,          // [131072][64]
                            const unsigned short* __restrict__ ws,
                            const float* __restrict__ b1p,        // [128]
                            const float* __restrict__ b1op,       // [128]
                            const float* __restrict__ b2p,        // [128]
                            const float* __restrict__ bvp,        // [16]
                            float* __restrict__ out) {            // [131072][16]
    // LDS: strides chosen so row-stride dwords ≡ 4 (mod 32) -> <=2-way bank conflicts.
    __shared__ __align__(16) unsigned short Xs[64][72];    // 9216 B  (64 feat + 8 wrap)
    __shared__ __align__(16) unsigned short Hc[64][264];   // 33792 B (cols 0..127 h1, 128..255 S/8)
    __shared__ __align__(16) unsigned short H2[64][136];   // 17408 B

    const int tid  = threadIdx.x;
    const int wid  = tid >> 6;         // 0..3
    const int lane = tid & 63;
    const int l15  = lane & 15;
    const int l16  = lane >> 4;        // 0..3
    const long R0  = (long)blockIdx.x * 64;

    const unsigned short* w1b  = ws;
    const unsigned short* w1ob = ws + 8192;
    const unsigned short* w2b  = ws + 16384;
    const unsigned short* wvb  = ws + 49152;

    // --- issue w1o B-fragment loads early (latency overlaps X staging) ---
    // B[k][j] = w1o[j][k]; frag: col j = n*16+l15, k = s*32 + l16*8 + e
    short8 bo[8][2];
    float b1o_r[8];
    #pragma unroll
    for (int n = 0; n < 8; ++n) {
        const int h = n * 16 + l15;
        bo[n][0] = *(const short8*)(w1ob + h * 64 + l16 * 8);
        bo[n][1] = *(const short8*)(w1ob + h * 64 + 32 + l16 * 8);
        b1o_r[n] = b1op[h];
    }

    // --- stage X tile: 64 rows x 64 f32 -> bf16 LDS, + 8-elem wraparound dup ---
    {
        const int r = tid >> 2, q = tid & 3;
        const float4v* src = (const float4v*)(X + (R0 + r) * 64 + q * 16);
        union { unsigned short u[16]; short8 v[2]; } t;
        #pragma unroll
        for (int i = 0; i < 4; ++i) {
            float4v f = src[i];
            t.u[4 * i + 0] = f2bf(f.x);
            t.u[4 * i + 1] = f2bf(f.y);
            t.u[4 * i + 2] = f2bf(f.z);
            t.u[4 * i + 3] = f2bf(f.w);
        }
        *(short8*)(&Xs[r][q * 16])     = t.v[0];
        *(short8*)(&Xs[r][q * 16 + 8]) = t.v[1];
        if (q == 0) *(short8*)(&Xs[r][64]) = t.v[0];   // wrap: elems 0..7 -> 64..71
    }
    __syncthreads();

    // --- per-wave A windows (rows 16*wid .. 16*wid+15), loaded ONCE for all 9 passes ---
    const int xrow = 16 * wid + l15;
    uintx4 v0lo = *(const uintx4*)(&Xs[xrow][l16 * 8]);
    uintx4 v0hi = *(const uintx4*)(&Xs[xrow][l16 * 8 + 8]);
    uintx4 v1lo = *(const uintx4*)(&Xs[xrow][32 + l16 * 8]);
    uintx4 v1hi = *(const uintx4*)(&Xs[xrow][40 + l16 * 8]);
    unsigned int u0[8] = {v0lo.x, v0lo.y, v0lo.z, v0lo.w, v0hi.x, v0hi.y, v0hi.z, v0hi.w};
    unsigned int u1[8] = {v1lo.x, v1lo.y, v1lo.z, v1lo.w, v1hi.x, v1hi.y, v1hi.z, v1hi.w};

    const floatx4 zf = {0.f, 0.f, 0.f, 0.f};

    // --- 8 rolled passes: pass kx computes, for batches {2*wid, 2*wid+1},
    //     S_{k=kx+1}[h] = sum_{j=1..7} relu( roll_{kx+1}(x_j) . w1o[h] + b1o[h] ) ---
    #pragma unroll
    for (int kx = 0; kx < 8; ++kx) {
        const int kk = kx + 1;          // roll amount, compile-time per unrolled iter
        const int c  = kk >> 1;
        union { unsigned int u[4]; short8 v; } A0, A1;
        #pragma unroll
        for (int d = 0; d < 4; ++d) {
            if (kk & 1) {
                A0.u[d] = (u0[d + c] >> 16) | (u0[d + c + 1] << 16);
                A1.u[d] = (u1[d + c] >> 16) | (u1[d + c + 1] << 16);
            } else {
                A0.u[d] = u0[d + c];
                A1.u[d] = u1[d + c];
            }
        }
        floatx4 acc[8];
        #pragma unroll
        for (int n = 0; n < 8; ++n) acc[n] = zf;
        #pragma unroll
        for (int n = 0; n < 8; ++n) {
            acc[n] = mfma16(A0.v, bo[n][0], acc[n]);
            acc[n] = mfma16(A1.v, bo[n][1], acc[n]);
        }
        // epilogue: bias+relu, sum rows 1..7 of each 8-row (=one batch) group
        #pragma unroll
        for (int n = 0; n < 8; ++n) {
            float r0 = fmaxf(acc[n].x + b1o_r[n], 0.f);   // C row = l16*4+0
            float r1 = fmaxf(acc[n].y + b1o_r[n], 0.f);
            float r2 = fmaxf(acc[n].z + b1o_r[n], 0.f);
            float r3 = fmaxf(acc[n].w + b1o_r[n], 0.f);
            // exclude j==0 rows (row%8==0 -> l16 even, reg 0)
            float t = r1 + r2 + r3 + (((l16 & 1) != 0) ? r0 : 0.f);
            float s = t + __shfl_xor(t, 16, 64);          // combine row-halves of each batch
            if ((lane & 16) == 0) {                       // l16==0 -> batch0, l16==2 -> batch1
                int row = 16 * wid + ((lane >> 5) << 3) + kx;   // agent i = kx
                Hc[row][128 + n * 16 + l15] = f2bf(s * 0.125f);
            }
        }
    }

    // --- h1 pass (roll 0, weights w1) ---
    {
        short8 b1fr[8][2];
        float b1_r[8];
        #pragma unroll
        for (int n = 0; n < 8; ++n) {
            const int h = n * 16 + l15;
            b1fr[n][0] = *(const short8*)(w1b + h * 64 + l16 * 8);
            b1fr[n][1] = *(const short8*)(w1b + h * 64 + 32 + l16 * 8);
            b1_r[n]    = b1p[h];
        }
        union { unsigned int u[4]; short8 v; } A0, A1;
        #pragma unroll
        for (int d = 0; d < 4; ++d) { A0.u[d] = u0[d]; A1.u[d] = u1[d]; }
        floatx4 acc[8];
        #pragma unroll
        for (int n = 0; n < 8; ++n) acc[n] = zf;
        #pragma unroll
        for (int n = 0; n < 8; ++n) {
            acc[n] = mfma16(A0.v, b1fr[n][0], acc[n]);
            acc[n] = mfma16(A1.v, b1fr[n][1], acc[n]);
        }
        #pragma unroll
        for (int n = 0; n < 8; ++n) {
            #pragma unroll
            for (int r = 0; r < 4; ++r) {
                int row = 16 * wid + l16 * 4 + r;
                Hc[row][n * 16 + l15] = f2bf(fmaxf(acc[n][r] + b1_r[n], 0.f));
            }
        }
    }

    // --- layer 2: h2 = relu(Hcat @ w2^T + b2). wave owns cols 32*wid..32*wid+31 ---
    short8 w2f[2][8];
    float b2_r[2];
    #pragma unroll
    for (int n = 0; n < 2; ++n) {
        const int h = wid * 32 + n * 16 + l15;
        b2_r[n] = b2p[h];
        #pragma unroll
        for (int s = 0; s < 8; ++s)
            w2f[n][s] = *(const short8*)(w2b + (size_t)h * 256 + s * 32 + l16 * 8);
    }
    __syncthreads();   // Hc complete

    #pragma unroll
    for (int mt = 0; mt < 4; ++mt) {
        floatx4 acc2[2] = {zf, zf};
        #pragma unroll
        for (int s = 0; s < 8; ++s) {
            short8 a = *(const short8*)(&Hc[mt * 16 + l15][s * 32 + l16 * 8]);
            acc2[0] = mfma16(a, w2f[0][s], acc2[0]);
            acc2[1] = mfma16(a, w2f[1][s], acc2[1]);
        }
        #pragma unroll
        for (int n = 0; n < 2; ++n) {
            #pragma unroll
            for (int r = 0; r < 4; ++r) {
                int row = mt * 16 + l16 * 4 + r;
                H2[row][wid * 32 + n * 16 + l15] = f2bf(fmaxf(acc2[n][r] + b2_r[n], 0.f));
            }
        }
    }

    // --- final layer: out = h2 @ wv^T + bv. wave owns rows 16*wid..+15 ---
    short8 wvf[4];
    #pragma unroll
    for (int s = 0; s < 4; ++s)
        wvf[s] = *(const short8*)(wvb + l15 * 128 + s * 32 + l16 * 8);
    const float bv_r = bvp[l15];
    __syncthreads();   // H2 complete

    {
        floatx4 acc4 = zf;
        #pragma unroll
        for (int s = 0; s < 4; ++s) {
            short8 a = *(const short8*)(&H2[wid * 16 + l15][s * 32 + l16 * 8]);
            acc4 = mfma16(a, wvf[s], acc4);
        }
        #pragma unroll
        for (int r = 0; r < 4; ++r) {
            long row = R0 + 16 * wid + l16 * 4 + r;
            out[row * 16 + l15] = acc4[r] + bv_r;
        }
    }
}

extern "C" void kernel_launch(void* const* d_in, const int* in_sizes, int n_in,
                              void* d_out, int out_size, void* d_ws, size_t ws_size,
                              hipStream_t stream) {
    (void)n_in; (void)out_size; (void)ws_size;
    const float* X   = (const float*)d_in[0];
    const float* w1  = (const float*)d_in[1];
    const float* b1  = (const float*)d_in[2];
    const float* w1o = (const float*)d_in[3];
    const float* b1o = (const float*)d_in[4];
    const float* w2  = (const float*)d_in[5];
    const float* b2  = (const float*)d_in[6];
    const float* wv  = (const float*)d_in[7];
    const float* bv  = (const float*)d_in[8];
    float* out = (float*)d_out;
    unsigned short* ws = (unsigned short*)d_ws;

    // weights -> bf16 (51200 elems, 200*256 threads exactly)
    cvt_weights<<<200, 256, 0, stream>>>(w1, w1o, w2, wv, ws);

    const int rows   = in_sizes[0] / 64;   // 131072
    const int blocks = rows / 64;          // 2048
    actor_fused<<<blocks, 256, 0, stream>>>(X, ws, b1, b1o, b2, bv, out);
}

// Round 2
// 68.692 us; speedup vs baseline: 1.1050x; 1.1050x over previous
//
#include <hip/hip_runtime.h>
#include <stdint.h>
#include <stddef.h>

// Actor_DeepSet: rows = 131072 (= 16384 batches x 8 agents), OBS=64, HIDDEN=128, OUT=16.
// Fully fused bf16-MFMA kernel: 64 rows (8 batches) per 256-thread block.
// R2: LDS aliased (H2 over dead Xs) 60416->51200 B => 3 blocks/CU; f2bf via
//     v_cvt_pk_bf16_f32 (1 VALU op) instead of 4-5-op manual RNE.

typedef __attribute__((ext_vector_type(8))) short short8;       // 8 x bf16 (4 VGPR)
typedef __attribute__((ext_vector_type(4))) float floatx4;      // MFMA C/D
typedef __attribute__((ext_vector_type(4))) unsigned int uintx4;
typedef __attribute__((ext_vector_type(4))) float float4v;

static __device__ __forceinline__ unsigned int cvtpk(float lo, float hi) {
    unsigned int r;
    asm("v_cvt_pk_bf16_f32 %0, %1, %2" : "=v"(r) : "v"(lo), "v"(hi));
    return r;
}
static __device__ __forceinline__ unsigned short f2bf(float f) {
    return (unsigned short)cvtpk(f, f);
}

static __device__ __forceinline__ floatx4 mfma16(short8 a, short8 b, floatx4 c) {
    return __builtin_amdgcn_mfma_f32_16x16x32_bf16(a, b, c, 0, 0, 0);
}

// ---- prologue: convert all weights to bf16 into d_ws ----
// ws layout (ushort elems): w1[8192] | w1o[8192] | w2[32768] | wv[2048]  (total 51200)
__global__ void cvt_weights(const float* __restrict__ w1, const float* __restrict__ w1o,
                            const float* __restrict__ w2, const float* __restrict__ wv,
                            unsigned short* __restrict__ ws) {
    int i = blockIdx.x * 256 + threadIdx.x;   // grid sized exactly 51200/256 = 200 blocks
    float v;
    if (i < 8192)       v = w1[i];
    else if (i < 16384) v = w1o[i - 8192];
    else if (i < 49152) v = w2[i - 16384];
    else                v = wv[i - 49152];
    ws[i] = f2bf(v);
}

__launch_bounds__(256, 3)
__global__ void actor_fused(const float* __restrict__ X,          // [131072][64]
                            const unsigned short* __restrict__ ws,
                            const float* __restrict__ b1p,        // [128]
                            const float* __restrict__ b1op,       // [128]
                            const float* __restrict__ b2p,        // [128]
                            const float* __restrict__ bvp,        // [16]
                            float* __restrict__ out) {            // [131072][16]
    // LDS: 51200 B total. Hc first; Xs and H2 ALIAS (Xs is dead before H2 is
    // first written - all Xs reads happen before the 2nd barrier, all H2
    // writes after it). Row strides ≡ 4 dwords (mod 32) -> <=2-way conflicts.
    __shared__ __align__(16) unsigned char smem[51200];
    unsigned short (*Hc)[264] = (unsigned short (*)[264])(smem);           // 33792 B
    unsigned short (*Xs)[72]  = (unsigned short (*)[72]) (smem + 33792);   //  9216 B
    unsigned short (*H2)[136] = (unsigned short (*)[136])(smem + 33792);   // 17408 B (alias)

    const int tid  = threadIdx.x;
    const int wid  = tid >> 6;         // 0..3
    const int lane = tid & 63;
    const int l15  = lane & 15;
    const int l16  = lane >> 4;        // 0..3
    const long R0  = (long)blockIdx.x * 64;

    const unsigned short* w1b  = ws;
    const unsigned short* w1ob = ws + 8192;
    const unsigned short* w2b  = ws + 16384;
    const unsigned short* wvb  = ws + 49152;

    // --- issue w1o B-fragment loads early (latency overlaps X staging) ---
    // B[k][j] = w1o[j][k]; frag: col j = n*16+l15, k = s*32 + l16*8 + e
    short8 bo[8][2];
    float b1o_r[8];
    #pragma unroll
    for (int n = 0; n < 8; ++n) {
        const int h = n * 16 + l15;
        bo[n][0] = *(const short8*)(w1ob + h * 64 + l16 * 8);
        bo[n][1] = *(const short8*)(w1ob + h * 64 + 32 + l16 * 8);
        b1o_r[n] = b1op[h];
    }

    // --- stage X tile: 64 rows x 64 f32 -> bf16 LDS, + 8-elem wraparound dup ---
    {
        const int r = tid >> 2, q = tid & 3;
        const float4v* src = (const float4v*)(X + (R0 + r) * 64 + q * 16);
        const float4v f0 = src[0], f1 = src[1], f2 = src[2], f3 = src[3];
        uintx4 lo, hi;
        lo.x = cvtpk(f0.x, f0.y); lo.y = cvtpk(f0.z, f0.w);
        lo.z = cvtpk(f1.x, f1.y); lo.w = cvtpk(f1.z, f1.w);
        hi.x = cvtpk(f2.x, f2.y); hi.y = cvtpk(f2.z, f2.w);
        hi.z = cvtpk(f3.x, f3.y); hi.w = cvtpk(f3.z, f3.w);
        *(uintx4*)(&Xs[r][q * 16])     = lo;
        *(uintx4*)(&Xs[r][q * 16 + 8]) = hi;
        if (q == 0) *(uintx4*)(&Xs[r][64]) = lo;   // wrap: elems 0..7 -> 64..71
    }
    __syncthreads();

    // --- per-wave A windows (rows 16*wid .. 16*wid+15), loaded ONCE for all 9 passes ---
    const int xrow = 16 * wid + l15;
    uintx4 v0lo = *(const uintx4*)(&Xs[xrow][l16 * 8]);
    uintx4 v0hi = *(const uintx4*)(&Xs[xrow][l16 * 8 + 8]);
    uintx4 v1lo = *(const uintx4*)(&Xs[xrow][32 + l16 * 8]);
    uintx4 v1hi = *(const uintx4*)(&Xs[xrow][40 + l16 * 8]);
    unsigned int u0[8] = {v0lo.x, v0lo.y, v0lo.z, v0lo.w, v0hi.x, v0hi.y, v0hi.z, v0hi.w};
    unsigned int u1[8] = {v1lo.x, v1lo.y, v1lo.z, v1lo.w, v1hi.x, v1hi.y, v1hi.z, v1hi.w};

    const floatx4 zf = {0.f, 0.f, 0.f, 0.f};

    // --- 8 rolled passes: pass kx computes, for batches {2*wid, 2*wid+1},
    //     S_{k=kx+1}[h] = sum_{j=1..7} relu( roll_{kx+1}(x_j) . w1o[h] + b1o[h] ) ---
    #pragma unroll
    for (int kx = 0; kx < 8; ++kx) {
        const int kk = kx + 1;          // roll amount, compile-time per unrolled iter
        const int c  = kk >> 1;
        union { unsigned int u[4]; short8 v; } A0, A1;
        #pragma unroll
        for (int d = 0; d < 4; ++d) {
            if (kk & 1) {
                A0.u[d] = (u0[d + c] >> 16) | (u0[d + c + 1] << 16);
                A1.u[d] = (u1[d + c] >> 16) | (u1[d + c + 1] << 16);
            } else {
                A0.u[d] = u0[d + c];
                A1.u[d] = u1[d + c];
            }
        }
        floatx4 acc[8];
        #pragma unroll
        for (int n = 0; n < 8; ++n) acc[n] = zf;
        #pragma unroll
        for (int n = 0; n < 8; ++n) {
            acc[n] = mfma16(A0.v, bo[n][0], acc[n]);
            acc[n] = mfma16(A1.v, bo[n][1], acc[n]);
        }
        // epilogue: bias+relu, sum rows 1..7 of each 8-row (=one batch) group
        #pragma unroll
        for (int n = 0; n < 8; ++n) {
            float r0 = fmaxf(acc[n].x + b1o_r[n], 0.f);   // C row = l16*4+0
            float r1 = fmaxf(acc[n].y + b1o_r[n], 0.f);
            float r2 = fmaxf(acc[n].z + b1o_r[n], 0.f);
            float r3 = fmaxf(acc[n].w + b1o_r[n], 0.f);
            // exclude j==0 rows (row%8==0 -> l16 even, reg 0)
            float t = r1 + r2 + r3 + (((l16 & 1) != 0) ? r0 : 0.f);
            float s = t + __shfl_xor(t, 16, 64);          // combine row-halves of each batch
            if ((lane & 16) == 0) {                       // l16==0 -> batch0, l16==2 -> batch1
                int row = 16 * wid + ((lane >> 5) << 3) + kx;   // agent i = kx
                Hc[row][128 + n * 16 + l15] = f2bf(s * 0.125f);
            }
        }
    }

    // --- h1 pass (roll 0, weights w1) ---
    {
        short8 b1fr[8][2];
        float b1_r[8];
        #pragma unroll
        for (int n = 0; n < 8; ++n) {
            const int h = n * 16 + l15;
            b1fr[n][0] = *(const short8*)(w1b + h * 64 + l16 * 8);
            b1fr[n][1] = *(const short8*)(w1b + h * 64 + 32 + l16 * 8);
            b1_r[n]    = b1p[h];
        }
        union { unsigned int u[4]; short8 v; } A0, A1;
        #pragma unroll
        for (int d = 0; d < 4; ++d) { A0.u[d] = u0[d]; A1.u[d] = u1[d]; }
        floatx4 acc[8];
        #pragma unroll
        for (int n = 0; n < 8; ++n) acc[n] = zf;
        #pragma unroll
        for (int n = 0; n < 8; ++n) {
            acc[n] = mfma16(A0.v, b1fr[n][0], acc[n]);
            acc[n] = mfma16(A1.v, b1fr[n][1], acc[n]);
        }
        #pragma unroll
        for (int n = 0; n < 8; ++n) {
            #pragma unroll
            for (int r = 0; r < 4; ++r) {
                int row = 16 * wid + l16 * 4 + r;
                Hc[row][n * 16 + l15] = f2bf(fmaxf(acc[n][r] + b1_r[n], 0.f));
            }
        }
    }

    // --- layer 2: h2 = relu(Hcat @ w2^T + b2). wave owns cols 32*wid..32*wid+31 ---
    short8 w2f[2][8];
    float b2_r[2];
    #pragma unroll
    for (int n = 0; n < 2; ++n) {
        const int h = wid * 32 + n * 16 + l15;
        b2_r[n] = b2p[h];
        #pragma unroll
        for (int s = 0; s < 8; ++s)
            w2f[n][s] = *(const short8*)(w2b + (size_t)h * 256 + s * 32 + l16 * 8);
    }
    __syncthreads();   // Hc complete; Xs dead from here on (H2 aliases it)

    #pragma unroll
    for (int mt = 0; mt < 4; ++mt) {
        floatx4 acc2[2] = {zf, zf};
        #pragma unroll
        for (int s = 0; s < 8; ++s) {
            short8 a = *(const short8*)(&Hc[mt * 16 + l15][s * 32 + l16 * 8]);
            acc2[0] = mfma16(a, w2f[0][s], acc2[0]);
            acc2[1] = mfma16(a, w2f[1][s], acc2[1]);
        }
        #pragma unroll
        for (int n = 0; n < 2; ++n) {
            #pragma unroll
            for (int r = 0; r < 4; ++r) {
                int row = mt * 16 + l16 * 4 + r;
                H2[row][wid * 32 + n * 16 + l15] = f2bf(fmaxf(acc2[n][r] + b2_r[n], 0.f));
            }
        }
    }

    // --- final layer: out = h2 @ wv^T + bv. wave owns rows 16*wid..+15 ---
    short8 wvf[4];
    #pragma unroll
    for (int s = 0; s < 4; ++s)
        wvf[s] = *(const short8*)(wvb + l15 * 128 + s * 32 + l16 * 8);
    const float bv_r = bvp[l15];
    __syncthreads();   // H2 complete

    {
        floatx4 acc4 = zf;
        #pragma unroll
        for (int s = 0; s < 4; ++s) {
            short8 a = *(const short8*)(&H2[wid * 16 + l15][s * 32 + l16 * 8]);
            acc4 = mfma16(a, wvf[s], acc4);
        }
        #pragma unroll
        for (int r = 0; r < 4; ++r) {
            long row = R0 + 16 * wid + l16 * 4 + r;
            out[row * 16 + l15] = acc4[r] + bv_r;
        }
    }
}

extern "C" void kernel_launch(void* const* d_in, const int* in_sizes, int n_in,
                              void* d_out, int out_size, void* d_ws, size_t ws_size,
                              hipStream_t stream) {
    (void)n_in; (void)out_size; (void)ws_size;
    const float* X   = (const float*)d_in[0];
    const float* w1  = (const float*)d_in[1];
    const float* b1  = (const float*)d_in[2];
    const float* w1o = (const float*)d_in[3];
    const float* b1o = (const float*)d_in[4];
    const float* w2  = (const float*)d_in[5];
    const float* b2  = (const float*)d_in[6];
    const float* wv  = (const float*)d_in[7];
    const float* bv  = (const float*)d_in[8];
    float* out = (float*)d_out;
    unsigned short* ws = (unsigned short*)d_ws;

    // weights -> bf16 (51200 elems, 200*256 threads exactly)
    cvt_weights<<<200, 256, 0, stream>>>(w1, w1o, w2, wv, ws);

    const int rows   = in_sizes[0] / 64;   // 131072
    const int blocks = rows / 64;          // 2048
    actor_fused<<<blocks, 256, 0, stream>>>(X, ws, b1, b1o, b2, bv, out);
}